// Round 3
// baseline (1888.197 us; speedup 1.0000x reference)
//
#include <hip/hip_runtime.h>
#include <math.h>

// Problem constants
#define BB   2
#define TT   2048
#define CC   1024
#define HH   16
#define DD   64
#define HID  256
#define FFD  4096
#define NTOK (BB*TT)        // 4096
#define CT   64             // scan chunk length
#define NC   (TT/CT)        // 32 chunks per sequence
#define NBH  (BB*HH)        // 32 sequences
#define NCHK (NBH*NC)       // 1024 chunk-blocks
#define MB   (1048576ULL)

typedef unsigned short u16;
typedef unsigned int   u32;

__device__ __forceinline__ float bf2f(u16 h){
    union { u32 u; float f; } c; c.u = ((u32)h) << 16; return c.f;
}
__device__ __forceinline__ u16 f2bf(float f){
    union { float f; u32 u; } c; c.f = f;
    u32 u = c.u;
    u += 0x7FFFu + ((u >> 16) & 1u);   // round-to-nearest-even
    return (u16)(u >> 16);
}
// idx >= 0: runtime flag (1 = f32). idx == -1: bf16. idx == -2: f32.
__device__ __forceinline__ bool is_f32(const u32* flags, int idx) {
    if (idx == -2) return true;
    if (idx < 0)  return false;
    return flags[idx] != 0;
}

// ---------------------------------------------------------------------------
// dtype sniffer: one wave. For each input, decide bf16 vs f32 by checking
// whether all sampled u16s look like sane bf16 (exp in [64,192) or exact +-0).
// fp32 data read as u16 has random low-halves -> fails with P ~ 1.
// ---------------------------------------------------------------------------
struct InPtrs { const void* p[11]; int n[11]; };

__global__ __launch_bounds__(64)
void sniff_kernel(InPtrs ip, u32* __restrict__ flags)
{
    int lane = threadIdx.x;
    u32 f0 = 0;
    for (int i = 0; i < 11; i++) {
        const u16* p = (const u16*)ip.p[i];
        int cap = ip.n[i] < 256 ? ip.n[i] : 256;
        bool ok = true;
        for (int j = lane; j < cap; j += 64) {
            u16 u = p[j];
            u32 e = (u >> 7) & 0xFFu;
            bool good = (u == 0u) || (u == 0x8000u) || (e >= 64u && e < 192u);
            ok = ok && good;
        }
        unsigned long long ball = __ballot(ok);
        u32 fl = (ball == ~0ull) ? 0u : 1u;
        if (ip.n[i] < 64) fl = f0;       // tiny tensors inherit x's dtype
        if (i == 0) f0 = fl;
        if (lane == 0) flags[i] = fl;
    }
}

// ---------------------------------------------------------------------------
// Generic NT GEMM: C[M,N] = epilogue( A[M,K] @ B[N,K]^T )
// A,B bf16 or f32 (runtime flag). MODE: 0 plain, 1 +bias+relu, 2 relu^2,
// 3 +res(bf16). M%128==0, N%128==0, K%16==0.
// 128x128 tile, BK=16, 256 threads, 8x8 per thread. fp32 accumulate.
// ---------------------------------------------------------------------------
template<int MODE>
__global__ __launch_bounds__(256)
void gemm_nt(const void* __restrict__ Av, const void* __restrict__ Bv,
             void* __restrict__ Cm, const void* __restrict__ aux,
             int M, int N, int K, const u32* __restrict__ flags,
             int ai, int bi, int xi, int oi)
{
    const bool af32 = is_f32(flags, ai);
    const bool bf32 = is_f32(flags, bi);
    const bool of32 = is_f32(flags, oi);

    __shared__ float As[16][128];
    __shared__ float Bs[16][128];
    const int tid  = threadIdx.x;
    const int bm   = blockIdx.y, bn = blockIdx.x;
    const int lrow = tid >> 1;            // 0..127
    const int lseg = (tid & 1) * 8;       // 0 or 8
    const size_t aoff = (size_t)(bm*128 + lrow)*K + lseg;
    const size_t boff = (size_t)(bn*128 + lrow)*K + lseg;

    float acc[8][8];
    #pragma unroll
    for (int i = 0; i < 8; i++)
        #pragma unroll
        for (int j = 0; j < 8; j++) acc[i][j] = 0.f;

    const int tm = (tid >> 4) * 8;        // 0..120
    const int tn = (tid & 15) * 8;

    for (int k0 = 0; k0 < K; k0 += 16) {
        float a8[8], b8[8];
        if (af32) {
            const float* p = (const float*)Av + aoff + k0;
            float4 u0 = *(const float4*)p;
            float4 u1 = *(const float4*)(p + 4);
            a8[0]=u0.x; a8[1]=u0.y; a8[2]=u0.z; a8[3]=u0.w;
            a8[4]=u1.x; a8[5]=u1.y; a8[6]=u1.z; a8[7]=u1.w;
        } else {
            const u16* p = (const u16*)Av + aoff + k0;
            uint4 au = *(const uint4*)p;
            u32 w[4] = {au.x, au.y, au.z, au.w};
            #pragma unroll
            for (int i = 0; i < 4; i++) {
                a8[2*i]   = bf2f((u16)(w[i] & 0xffffu));
                a8[2*i+1] = bf2f((u16)(w[i] >> 16));
            }
        }
        if (bf32) {
            const float* p = (const float*)Bv + boff + k0;
            float4 u0 = *(const float4*)p;
            float4 u1 = *(const float4*)(p + 4);
            b8[0]=u0.x; b8[1]=u0.y; b8[2]=u0.z; b8[3]=u0.w;
            b8[4]=u1.x; b8[5]=u1.y; b8[6]=u1.z; b8[7]=u1.w;
        } else {
            const u16* p = (const u16*)Bv + boff + k0;
            uint4 bu = *(const uint4*)p;
            u32 w[4] = {bu.x, bu.y, bu.z, bu.w};
            #pragma unroll
            for (int i = 0; i < 4; i++) {
                b8[2*i]   = bf2f((u16)(w[i] & 0xffffu));
                b8[2*i+1] = bf2f((u16)(w[i] >> 16));
            }
        }
        __syncthreads();
        #pragma unroll
        for (int i = 0; i < 8; i++) {
            As[lseg + i][lrow] = a8[i];
            Bs[lseg + i][lrow] = b8[i];
        }
        __syncthreads();
        #pragma unroll
        for (int kk = 0; kk < 16; kk++) {
            float a[8], b[8];
            *(float4*)(&a[0]) = *(const float4*)(&As[kk][tm]);
            *(float4*)(&a[4]) = *(const float4*)(&As[kk][tm + 4]);
            *(float4*)(&b[0]) = *(const float4*)(&Bs[kk][tn]);
            *(float4*)(&b[4]) = *(const float4*)(&Bs[kk][tn + 4]);
            #pragma unroll
            for (int i = 0; i < 8; i++)
                #pragma unroll
                for (int j = 0; j < 8; j++)
                    acc[i][j] = fmaf(a[i], b[j], acc[i][j]);
        }
    }

    const bool xf32 = is_f32(flags, xi);
    const int grow = bm*128 + tm;
    const int gcol = bn*128 + tn;
    #pragma unroll
    for (int i = 0; i < 8; i++) {
        size_t base = (size_t)(grow + i) * N + gcol;
        #pragma unroll
        for (int j = 0; j < 8; j++) {
            float vv = acc[i][j];
            if constexpr (MODE == 1) {
                float bia = xf32 ? ((const float*)aux)[gcol + j]
                                 : bf2f(((const u16*)aux)[gcol + j]);
                vv = fmaxf(vv + bia, 0.f);
            }
            if constexpr (MODE == 2) {
                vv = fmaxf(vv, 0.f);
                vv = vv * vv;
            }
            if constexpr (MODE == 3) {
                vv += bf2f(((const u16*)aux)[base + j]);   // residual: always bf16 (mine)
            }
            if (of32) ((float*)Cm)[base + j] = vv;
            else      ((u16*)Cm)[base + j]   = f2bf(vv);
        }
    }
}

// ---------------------------------------------------------------------------
// meta2: sur = sigmoid(hid @ Wm2^T + bm2); g = sur, dec = 1 - sur
// hid f32 [4096,256] (mine), Wm2/bm2 from d_in (runtime dtype).
// ---------------------------------------------------------------------------
__global__ __launch_bounds__(256)
void meta2_kernel(const float* __restrict__ hid, const void* __restrict__ Wm2,
                  const void* __restrict__ bm2, float* __restrict__ g,
                  float* __restrict__ dec, const u32* __restrict__ flags)
{
    const bool wf = is_f32(flags, 6);
    const bool bf = is_f32(flags, 7);
    __shared__ float hs[16][257];
    __shared__ float wsm[16][257];
    int tid  = threadIdx.x;
    int tok0 = blockIdx.x * 16;
    for (int i = tid; i < 16*256; i += 256) {
        wsm[i >> 8][i & 255] = wf ? ((const float*)Wm2)[i] : bf2f(((const u16*)Wm2)[i]);
        hs [i >> 8][i & 255] = hid[(size_t)tok0*256 + i];
    }
    __syncthreads();
    int tok = tid >> 4, hh = tid & 15;
    float s = 0.f;
    #pragma unroll 8
    for (int kk = 0; kk < 256; kk++) s = fmaf(hs[tok][kk], wsm[hh][kk], s);
    s += bf ? ((const float*)bm2)[hh] : bf2f(((const u16*)bm2)[hh]);
    float sg = 1.f / (1.f + expf(-s));
    int idx = (tok0 + tok) * HH + hh;
    g[idx]   = sg;
    dec[idx] = 1.f - sg;
}

// ---------------------------------------------------------------------------
// scan pass 1: per (b,h,chunk): M_c[d][e] = sum_s g_s * prod_{r>s} d_r * k_s[d] v_s[e]
//              P_c = prod_{chunk} d_r.   k,v bf16 (mine).
// ---------------------------------------------------------------------------
__global__ __launch_bounds__(256)
void scan_pass1(const u16* __restrict__ kbuf, const u16* __restrict__ vbuf,
                const float* __restrict__ g, const float* __restrict__ dec,
                float* __restrict__ Mb, float* __restrict__ Pb)
{
    __shared__ float ks[64*64];
    __shared__ float vs[64*64];
    __shared__ float dd[64], gg[64], cum[64], sw[64];
    int tid = threadIdx.x;
    int bhc = blockIdx.x;
    int c = bhc & 31, h = (bhc >> 5) & 15, b = bhc >> 9;
    int t0 = c * CT;
    size_t rowbase = ((size_t)(b*TT + t0))*CC + h*DD;

    for (int i = tid; i < 4096; i += 256) {
        int s = i >> 6, d = i & 63;
        ks[i] = bf2f(kbuf[rowbase + (size_t)s*CC + d]);
        vs[i] = bf2f(vbuf[rowbase + (size_t)s*CC + d]);
    }
    if (tid < 64) {
        int gidx = (b*TT + t0 + tid)*HH + h;
        dd[tid] = dec[gidx];
        gg[tid] = g[gidx];
    }
    __syncthreads();
    if (tid == 0) {
        float cs = 0.f;
        for (int s = 0; s < 64; s++) { cs += logf(fmaxf(dd[s], 1e-30f)); cum[s] = cs; }
    }
    __syncthreads();
    float ctot = cum[63];
    if (tid < 64) sw[tid] = gg[tid] * expf(ctot - cum[tid]);
    __syncthreads();

    int d0 = (tid >> 4) * 4, e0 = (tid & 15) * 4;
    float m[4][4] = {};
    for (int s = 0; s < 64; s++) {
        float w = sw[s];
        float4 kv = *(const float4*)&ks[s*64 + d0];
        float4 vv = *(const float4*)&vs[s*64 + e0];
        float a0 = w*kv.x, a1 = w*kv.y, a2 = w*kv.z, a3 = w*kv.w;
        m[0][0]=fmaf(a0,vv.x,m[0][0]); m[0][1]=fmaf(a0,vv.y,m[0][1]); m[0][2]=fmaf(a0,vv.z,m[0][2]); m[0][3]=fmaf(a0,vv.w,m[0][3]);
        m[1][0]=fmaf(a1,vv.x,m[1][0]); m[1][1]=fmaf(a1,vv.y,m[1][1]); m[1][2]=fmaf(a1,vv.z,m[1][2]); m[1][3]=fmaf(a1,vv.w,m[1][3]);
        m[2][0]=fmaf(a2,vv.x,m[2][0]); m[2][1]=fmaf(a2,vv.y,m[2][1]); m[2][2]=fmaf(a2,vv.z,m[2][2]); m[2][3]=fmaf(a2,vv.w,m[2][3]);
        m[3][0]=fmaf(a3,vv.x,m[3][0]); m[3][1]=fmaf(a3,vv.y,m[3][1]); m[3][2]=fmaf(a3,vv.z,m[3][2]); m[3][3]=fmaf(a3,vv.w,m[3][3]);
    }
    size_t base = (size_t)bhc * 4096;
    #pragma unroll
    for (int i = 0; i < 4; i++) {
        float4 o = make_float4(m[i][0], m[i][1], m[i][2], m[i][3]);
        *(float4*)&Mb[base + (size_t)(d0 + i)*64 + e0] = o;
    }
    if (tid == 0) Pb[bhc] = expf(ctot);
}

// ---------------------------------------------------------------------------
// scan pass 2 (IN PLACE): MS holds M_c in; out = S_c (state at chunk start).
// ---------------------------------------------------------------------------
__global__ __launch_bounds__(256)
void scan_pass2(float* __restrict__ MS, const float* __restrict__ Pb)
{
    int bh = blockIdx.x, tid = threadIdx.x;
    float st[16];
    #pragma unroll
    for (int i = 0; i < 16; i++) st[i] = 0.f;
    for (int c = 0; c < NC; c++) {
        size_t base = ((size_t)bh*NC + c) * 4096;
        float p = Pb[bh*NC + c];
        #pragma unroll
        for (int i = 0; i < 16; i++) {
            size_t e = base + tid + i*256;
            float m = MS[e];
            MS[e] = st[i];
            st[i] = fmaf(p, st[i], m);
        }
    }
}

// ---------------------------------------------------------------------------
// fused scan pass 3: A[t][s] = (s<=t)? g_s exp(cum[t]-cum[s]) (q_t.k_s) : 0
//   y[t] = A @ v + exp(cum[t]) * (q_t @ S_c)
// y is written OVER the q buffer (exact same addresses this block read).
// ---------------------------------------------------------------------------
__global__ __launch_bounds__(256)
void scan_pass3(const u16* __restrict__ qbuf, const u16* __restrict__ kbuf,
                const u16* __restrict__ vbuf, const float* __restrict__ g,
                const float* __restrict__ dec, const float* __restrict__ Sb,
                u16* __restrict__ y)
{
    __shared__ float qs[64*64];     // [t][d]
    __shared__ float kt[64*68];     // [d][s] padded; later reused as Ss [d][e]
    __shared__ float vs[64*64];     // [s][e]
    __shared__ u16   Aws[4096];     // [t][s]
    __shared__ float dd[64], gg[64], cum[64];
    int tid = threadIdx.x;
    int bhc = blockIdx.x;
    int c = bhc & 31, h = (bhc >> 5) & 15, b = bhc >> 9;
    int t0 = c * CT;
    size_t rowbase = ((size_t)(b*TT + t0))*CC + h*DD;

    for (int i = tid; i < 4096; i += 256) {
        int s = i >> 6, d = i & 63;
        size_t gi = rowbase + (size_t)s*CC + d;
        qs[i]        = bf2f(qbuf[gi]);
        kt[d*68 + s] = bf2f(kbuf[gi]);
        vs[i]        = bf2f(vbuf[gi]);
    }
    if (tid < 64) {
        int gidx = (b*TT + t0 + tid)*HH + h;
        dd[tid] = dec[gidx];
        gg[tid] = g[gidx];
    }
    __syncthreads();
    if (tid == 0) {
        float cs = 0.f;
        for (int s = 0; s < 64; s++) { cs += logf(fmaxf(dd[s], 1e-30f)); cum[s] = cs; }
    }
    __syncthreads();

    const int tt0 = (tid >> 4) * 4, ss0 = (tid & 15) * 4;
    float a1[4][4] = {};
    for (int d = 0; d < 64; d++) {
        float4 kv = *(const float4*)&kt[d*68 + ss0];
        #pragma unroll
        for (int i = 0; i < 4; i++) {
            float qv = qs[(tt0 + i)*64 + d];
            a1[i][0] = fmaf(qv, kv.x, a1[i][0]);
            a1[i][1] = fmaf(qv, kv.y, a1[i][1]);
            a1[i][2] = fmaf(qv, kv.z, a1[i][2]);
            a1[i][3] = fmaf(qv, kv.w, a1[i][3]);
        }
    }
    #pragma unroll
    for (int i = 0; i < 4; i++) {
        int t = tt0 + i;
        float ct = cum[t];
        #pragma unroll
        for (int j = 0; j < 4; j++) {
            int s = ss0 + j;
            float w = (s <= t) ? gg[s] * expf(ct - cum[s]) : 0.f;
            Aws[t*64 + s] = f2bf(w * a1[i][j]);
        }
    }
    __syncthreads();                 // all kt reads done
    float* Ss = kt;                  // reuse kt region for state (4096 floats)
    size_t sbase = (size_t)bhc * 4096;
    for (int i = tid; i < 4096; i += 256) Ss[i] = Sb[sbase + i];
    __syncthreads();

    const int e0 = ss0;
    float o1[4][4] = {}, o2[4][4] = {};
    for (int s = 0; s < 64; s++) {
        float4 vv = *(const float4*)&vs[s*64 + e0];
        #pragma unroll
        for (int i = 0; i < 4; i++) {
            float av = bf2f(Aws[(tt0 + i)*64 + s]);
            o1[i][0] = fmaf(av, vv.x, o1[i][0]);
            o1[i][1] = fmaf(av, vv.y, o1[i][1]);
            o1[i][2] = fmaf(av, vv.z, o1[i][2]);
            o1[i][3] = fmaf(av, vv.w, o1[i][3]);
        }
    }
    for (int d = 0; d < 64; d++) {
        float4 sv = *(const float4*)&Ss[d*64 + e0];
        #pragma unroll
        for (int i = 0; i < 4; i++) {
            float qv = qs[(tt0 + i)*64 + d];
            o2[i][0] = fmaf(qv, sv.x, o2[i][0]);
            o2[i][1] = fmaf(qv, sv.y, o2[i][1]);
            o2[i][2] = fmaf(qv, sv.z, o2[i][2]);
            o2[i][3] = fmaf(qv, sv.w, o2[i][3]);
        }
    }
    #pragma unroll
    for (int i = 0; i < 4; i++) {
        float cd = expf(cum[tt0 + i]);
        size_t obase = rowbase + (size_t)(tt0 + i)*CC + e0;
        #pragma unroll
        for (int j = 0; j < 4; j++)
            y[obase + j] = f2bf(fmaf(cd, o2[i][j], o1[i][j]));
    }
}

// ---------------------------------------------------------------------------
// rmsnorm per row of 1024 (bf16 in, bf16 out)
// ---------------------------------------------------------------------------
__global__ __launch_bounds__(256)
void rmsnorm_kernel(const u16* __restrict__ yp, u16* __restrict__ yn)
{
    __shared__ float red[4];
    __shared__ float sscale;
    int row = blockIdx.x, tid = threadIdx.x;
    size_t base = (size_t)row*CC + tid*4;
    uint2 w = *(const uint2*)(yp + base);
    float v0 = bf2f((u16)(w.x & 0xffffu)), v1 = bf2f((u16)(w.x >> 16));
    float v2 = bf2f((u16)(w.y & 0xffffu)), v3 = bf2f((u16)(w.y >> 16));
    float p = v0*v0 + v1*v1 + v2*v2 + v3*v3;
    #pragma unroll
    for (int off = 32; off > 0; off >>= 1) p += __shfl_down(p, off, 64);
    if ((tid & 63) == 0) red[tid >> 6] = p;
    __syncthreads();
    if (tid == 0) {
        float tot = red[0] + red[1] + red[2] + red[3];
        sscale = rsqrtf(tot * (1.0f/1024.0f) + 1.1920928955078125e-07f);
    }
    __syncthreads();
    float sc = sscale;
    yn[base + 0] = f2bf(v0 * sc);
    yn[base + 1] = f2bf(v1 * sc);
    yn[base + 2] = f2bf(v2 * sc);
    yn[base + 3] = f2bf(v3 * sc);
}

// ---------------------------------------------------------------------------
// Workspace layout (peak 48 MB + 64 B):
//   q (=yat after pass3) bf16 8 MB @ 0
//   k    bf16  8 MB @  8 MB
//   v    bf16  8 MB @ 16 MB
//   hid  f32   4 MB @ 24 MB
//   g    f32 .25 MB @ 28 MB ; dec @ 28.25 MB ; Pb @ 28.5 MB
//   MS   f32  16 MB @ 29 MB  (M_c then S_c in place; dead after pass3)
//   yn   bf16  8 MB @ 32 MB  (over dead MS)
//   ypr  bf16  8 MB @ 40 MB  (over dead MS tail + fresh)
//   h1   bf16 32 MB @  0     (over q,k,v,hid,g,dec,Pb,MS-head — all dead at fc)
//   flags u32 @ 48 MB
// ---------------------------------------------------------------------------
extern "C" void kernel_launch(void* const* d_in, const int* in_sizes, int n_in,
                              void* d_out, int out_size, void* d_ws, size_t ws_size,
                              hipStream_t stream)
{
    char* ws = (char*)d_ws;
    u16*   q    = (u16*)  (ws + 0*MB);
    u16*   k    = (u16*)  (ws + 8*MB);
    u16*   v    = (u16*)  (ws + 16*MB);
    float* hid  = (float*)(ws + 24*MB);
    float* g    = (float*)(ws + 28*MB);
    float* dec  = (float*)(ws + 28*MB + 262144);
    float* Pb   = (float*)(ws + 28*MB + 524288);
    float* MS   = (float*)(ws + 29*MB);
    u16*   yat  = q;                      // pass3 writes over q (safe: exact alias)
    u16*   yn   = (u16*)  (ws + 32*MB);
    u16*   ypr  = (u16*)  (ws + 40*MB);
    u16*   h1   = (u16*)  (ws + 0*MB);
    u32*   flags= (u32*)  (ws + 48*MB);

    const void* x   = d_in[0];
    const void* Wq  = d_in[1];
    const void* Wk  = d_in[2];
    const void* Wv  = d_in[3];
    const void* Wm1 = d_in[4];
    const void* bm1 = d_in[5];
    const void* Wm2 = d_in[6];
    const void* bm2 = d_in[7];
    const void* Wpr = d_in[8];
    const void* Wfc = d_in[9];
    const void* Wcp = d_in[10];

    InPtrs ip;
    for (int i = 0; i < 11; i++) { ip.p[i] = d_in[i]; ip.n[i] = in_sizes[i]; }
    sniff_kernel<<<1, 64, 0, stream>>>(ip, flags);

    // meta net: hid = relu(x @ Wm1^T + bm1)  (f32 out)
    gemm_nt<1><<<dim3(2, 32), 256, 0, stream>>>(x, Wm1, hid, bm1, NTOK, HID, CC, flags, 0, 4, 5, -2);
    meta2_kernel<<<NTOK/16, 256, 0, stream>>>(hid, Wm2, bm2, g, dec, flags);
    // qkv (bf16 out)
    gemm_nt<0><<<dim3(8, 32), 256, 0, stream>>>(x, Wq, q, nullptr, NTOK, CC, CC, flags, 0, 1, -1, -1);
    gemm_nt<0><<<dim3(8, 32), 256, 0, stream>>>(x, Wk, k, nullptr, NTOK, CC, CC, flags, 0, 2, -1, -1);
    gemm_nt<0><<<dim3(8, 32), 256, 0, stream>>>(x, Wv, v, nullptr, NTOK, CC, CC, flags, 0, 3, -1, -1);
    // chunked gated linear-attention scan
    scan_pass1<<<NCHK, 256, 0, stream>>>(k, v, g, dec, MS, Pb);
    scan_pass2<<<NBH, 256, 0, stream>>>(MS, Pb);
    scan_pass3<<<NCHK, 256, 0, stream>>>(q, k, v, g, dec, MS, yat);
    // proj + rmsnorm + squared-relu MLP (+ residual in last GEMM)
    gemm_nt<0><<<dim3(8, 32), 256, 0, stream>>>(yat, Wpr, ypr, nullptr, NTOK, CC, CC, flags, -1, 8, -1, -1);
    rmsnorm_kernel<<<NTOK, 256, 0, stream>>>(ypr, yn);
    gemm_nt<2><<<dim3(32, 32), 256, 0, stream>>>(yn, Wfc, h1, nullptr, NTOK, FFD, CC, flags, -1, 9, -1, -1);
    // out dtype follows x's dtype (flags[0])
    gemm_nt<3><<<dim3(8, 32), 256, 0, stream>>>(h1, Wcp, d_out, ypr, NTOK, CC, FFD, flags, -1, 10, -1, 0);
}

// Round 5
// 750.238 us; speedup vs baseline: 2.5168x; 2.5168x over previous
//
#include <hip/hip_runtime.h>
#include <math.h>

// Problem constants
#define BB   2
#define TT   2048
#define CC   1024
#define HH   16
#define DD   64
#define HID  256
#define FFD  4096
#define NTOK (BB*TT)        // 4096
#define CT   64             // scan chunk length
#define NC   (TT/CT)        // 32 chunks per sequence
#define NBH  (BB*HH)        // 32 sequences
#define NCHK (NBH*NC)       // 1024 chunk-blocks
#define MB   (1048576ULL)

typedef unsigned short u16;
typedef unsigned int   u32;
typedef __attribute__((ext_vector_type(8))) short frag8;   // 8 bf16 = 4 VGPRs
typedef __attribute__((ext_vector_type(4))) float f32x4;

__device__ __forceinline__ float bf2f(u16 h){
    union { u32 u; float f; } c; c.u = ((u32)h) << 16; return c.f;
}
__device__ __forceinline__ u16 f2bf(float f){
    union { float f; u32 u; } c; c.f = f;
    u32 u = c.u;
    u += 0x7FFFu + ((u >> 16) & 1u);   // RNE
    return (u16)(u >> 16);
}
// idx >= 0: runtime flag (1 = f32). idx == -1: bf16. idx == -2: f32.
__device__ __forceinline__ bool is_f32(const u32* flags, int idx) {
    if (idx == -2) return true;
    if (idx < 0)  return false;
    return flags[idx] != 0;
}

// ---------------------------------------------------------------------------
// dtype sniffer (identical to passing round-3 version)
// ---------------------------------------------------------------------------
struct InPtrs { const void* p[11]; int n[11]; };

__global__ __launch_bounds__(64)
void sniff_kernel(InPtrs ip, u32* __restrict__ flags)
{
    int lane = threadIdx.x;
    u32 f0 = 0;
    for (int i = 0; i < 11; i++) {
        const u16* p = (const u16*)ip.p[i];
        int cap = ip.n[i] < 256 ? ip.n[i] : 256;
        bool ok = true;
        for (int j = lane; j < cap; j += 64) {
            u16 u = p[j];
            u32 e = (u >> 7) & 0xFFu;
            bool good = (u == 0u) || (u == 0x8000u) || (e >= 64u && e < 192u);
            ok = ok && good;
        }
        unsigned long long ball = __ballot(ok);
        u32 fl = (ball == ~0ull) ? 0u : 1u;
        if (ip.n[i] < 64) fl = f0;       // tiny tensors inherit x's dtype
        if (i == 0) f0 = fl;
        if (lane == 0) flags[i] = fl;
    }
}

// ---------------------------------------------------------------------------
// NT GEMM, MFMA core: C[M,N] = epilogue( A[M,K] @ B[N,K]^T )
// A,B bf16 or f32 (runtime flag), staged to LDS as bf16. fp32 accumulate.
// MODE: 0 plain, 1 +bias+relu, 2 relu^2, 3 +res(bf16).
// 128x128 tile, BK=32, 256 thr = 4 waves, each wave 4x4 of 16x16x32 MFMA.
// LDS row stride 40 u16 (80 B). Requires M%128==0, N%128==0, K%32==0.
// ---------------------------------------------------------------------------
template<int MODE>
__global__ __launch_bounds__(256)
void gemm_nt(const void* __restrict__ Av, const void* __restrict__ Bv,
             void* __restrict__ Cm, const void* __restrict__ aux,
             int M, int N, int K, const u32* __restrict__ flags,
             int ai, int bi, int xi, int oi)
{
    const bool af32 = is_f32(flags, ai);
    const bool bf32 = is_f32(flags, bi);
    const bool of32 = is_f32(flags, oi);

    constexpr int LDK = 40;
    __shared__ u16 As[128 * LDK];
    __shared__ u16 Bs[128 * LDK];
    const int tid  = threadIdx.x;
    const int bm = blockIdx.y, bn = blockIdx.x;
    const int row  = tid >> 1;          // 0..127
    const int half = tid & 1;           // which 16-element k-chunk
    const size_t aoff = (size_t)(bm*128 + row)*K + half*16;
    const size_t boff = (size_t)(bn*128 + row)*K + half*16;
    u16* sA = &As[row*LDK + half*16];
    u16* sB = &Bs[row*LDK + half*16];

    const int wave = tid >> 6, lane = tid & 63;
    const int lm = lane & 15, quad = lane >> 4;
    const int wm = (wave >> 1) * 64, wn = (wave & 1) * 64;

    f32x4 acc[4][4];
    #pragma unroll
    for (int i = 0; i < 4; i++)
        #pragma unroll
        for (int j = 0; j < 4; j++)
            acc[i][j] = (f32x4){0.f, 0.f, 0.f, 0.f};

    for (int k0 = 0; k0 < K; k0 += 32) {
        u16 abuf[16], bbuf[16];
        if (af32) {
            const float* p = (const float*)Av + aoff + k0;
            #pragma unroll
            for (int i = 0; i < 16; i += 4) {
                float4 u = *(const float4*)(p + i);
                abuf[i]   = f2bf(u.x); abuf[i+1] = f2bf(u.y);
                abuf[i+2] = f2bf(u.z); abuf[i+3] = f2bf(u.w);
            }
        } else {
            const u16* p = (const u16*)Av + aoff + k0;
            *(uint4*)abuf     = *(const uint4*)p;
            *(uint4*)(abuf+8) = *(const uint4*)(p + 8);
        }
        if (bf32) {
            const float* p = (const float*)Bv + boff + k0;
            #pragma unroll
            for (int i = 0; i < 16; i += 4) {
                float4 u = *(const float4*)(p + i);
                bbuf[i]   = f2bf(u.x); bbuf[i+1] = f2bf(u.y);
                bbuf[i+2] = f2bf(u.z); bbuf[i+3] = f2bf(u.w);
            }
        } else {
            const u16* p = (const u16*)Bv + boff + k0;
            *(uint4*)bbuf     = *(const uint4*)p;
            *(uint4*)(bbuf+8) = *(const uint4*)(p + 8);
        }
        __syncthreads();
        *(uint4*)sA = *(uint4*)abuf; *(uint4*)(sA + 8) = *(uint4*)(abuf + 8);
        *(uint4*)sB = *(uint4*)bbuf; *(uint4*)(sB + 8) = *(uint4*)(bbuf + 8);
        __syncthreads();
        frag8 af[4], bf[4];
        #pragma unroll
        for (int i = 0; i < 4; i++) {
            af[i] = *(frag8*)&As[(wm + i*16 + lm)*LDK + quad*8];
            bf[i] = *(frag8*)&Bs[(wn + i*16 + lm)*LDK + quad*8];
        }
        #pragma unroll
        for (int i = 0; i < 4; i++)
            #pragma unroll
            for (int j = 0; j < 4; j++)
                acc[i][j] = __builtin_amdgcn_mfma_f32_16x16x32_bf16(
                    af[i], bf[j], acc[i][j], 0, 0, 0);
    }

    const bool xf32 = is_f32(flags, xi);
    // C/D map (m89/m91): col = lane&15, row = quad*4 + reg
    #pragma unroll
    for (int i = 0; i < 4; i++) {
        #pragma unroll
        for (int j = 0; j < 4; j++) {
            const int gcol = bn*128 + wn + j*16 + lm;
            #pragma unroll
            for (int r = 0; r < 4; r++) {
                const int grow = bm*128 + wm + i*16 + quad*4 + r;
                size_t off = (size_t)grow * N + gcol;
                float vv = acc[i][j][r];
                if constexpr (MODE == 1) {
                    float bia = xf32 ? ((const float*)aux)[gcol]
                                     : bf2f(((const u16*)aux)[gcol]);
                    vv = fmaxf(vv + bia, 0.f);
                }
                if constexpr (MODE == 2) { vv = fmaxf(vv, 0.f); vv = vv * vv; }
                if constexpr (MODE == 3) { vv += bf2f(((const u16*)aux)[off]); }
                if (of32) ((float*)Cm)[off] = vv;
                else      ((u16*)Cm)[off]   = f2bf(vv);
            }
        }
    }
}

// ---------------------------------------------------------------------------
// meta2: sur = sigmoid(hid @ Wm2^T + bm2); g = sur, dec = 1 - sur
// ---------------------------------------------------------------------------
__global__ __launch_bounds__(256)
void meta2_kernel(const float* __restrict__ hid, const void* __restrict__ Wm2,
                  const void* __restrict__ bm2, float* __restrict__ g,
                  float* __restrict__ dec, const u32* __restrict__ flags)
{
    const bool wf = is_f32(flags, 6);
    const bool bf = is_f32(flags, 7);
    __shared__ float hs[16][257];
    __shared__ float wsm[16][257];
    int tid  = threadIdx.x;
    int tok0 = blockIdx.x * 16;
    for (int i = tid; i < 16*256; i += 256) {
        wsm[i >> 8][i & 255] = wf ? ((const float*)Wm2)[i] : bf2f(((const u16*)Wm2)[i]);
        hs [i >> 8][i & 255] = hid[(size_t)tok0*256 + i];
    }
    __syncthreads();
    int tok = tid >> 4, hh = tid & 15;
    float s = 0.f;
    #pragma unroll 8
    for (int kk = 0; kk < 256; kk++) s = fmaf(hs[tok][kk], wsm[hh][kk], s);
    s += bf ? ((const float*)bm2)[hh] : bf2f(((const u16*)bm2)[hh]);
    float sg = 1.f / (1.f + expf(-s));
    int idx = (tok0 + tok) * HH + hh;
    g[idx]   = sg;
    dec[idx] = 1.f - sg;
}

// ---------------------------------------------------------------------------
// scan pass 1: M_c[d][e] = sum_s g_s * prod_{r>s} d_r * k_s[d] v_s[e];  P_c
// ---------------------------------------------------------------------------
__global__ __launch_bounds__(256)
void scan_pass1(const u16* __restrict__ kbuf, const u16* __restrict__ vbuf,
                const float* __restrict__ g, const float* __restrict__ dec,
                float* __restrict__ Mb, float* __restrict__ Pb)
{
    __shared__ float ks[64*64];
    __shared__ float vs[64*64];
    __shared__ float dd[64], gg[64], cum[64], sw[64];
    int tid = threadIdx.x;
    int bhc = blockIdx.x;
    int c = bhc & 31, h = (bhc >> 5) & 15, b = bhc >> 9;
    int t0 = c * CT;
    size_t rowbase = ((size_t)(b*TT + t0))*CC + h*DD;

    for (int i = tid; i < 4096; i += 256) {
        int s = i >> 6, d = i & 63;
        ks[i] = bf2f(kbuf[rowbase + (size_t)s*CC + d]);
        vs[i] = bf2f(vbuf[rowbase + (size_t)s*CC + d]);
    }
    if (tid < 64) {
        int gidx = (b*TT + t0 + tid)*HH + h;
        dd[tid] = dec[gidx];
        gg[tid] = g[gidx];
    }
    __syncthreads();
    if (tid == 0) {
        float cs = 0.f;
        for (int s = 0; s < 64; s++) { cs += logf(fmaxf(dd[s], 1e-30f)); cum[s] = cs; }
    }
    __syncthreads();
    float ctot = cum[63];
    if (tid < 64) sw[tid] = gg[tid] * expf(ctot - cum[tid]);
    __syncthreads();

    int d0 = (tid >> 4) * 4, e0 = (tid & 15) * 4;
    float m[4][4] = {};
    for (int s = 0; s < 64; s++) {
        float w = sw[s];
        float4 kv = *(const float4*)&ks[s*64 + d0];
        float4 vv = *(const float4*)&vs[s*64 + e0];
        float a0 = w*kv.x, a1 = w*kv.y, a2 = w*kv.z, a3 = w*kv.w;
        m[0][0]=fmaf(a0,vv.x,m[0][0]); m[0][1]=fmaf(a0,vv.y,m[0][1]); m[0][2]=fmaf(a0,vv.z,m[0][2]); m[0][3]=fmaf(a0,vv.w,m[0][3]);
        m[1][0]=fmaf(a1,vv.x,m[1][0]); m[1][1]=fmaf(a1,vv.y,m[1][1]); m[1][2]=fmaf(a1,vv.z,m[1][2]); m[1][3]=fmaf(a1,vv.w,m[1][3]);
        m[2][0]=fmaf(a2,vv.x,m[2][0]); m[2][1]=fmaf(a2,vv.y,m[2][1]); m[2][2]=fmaf(a2,vv.z,m[2][2]); m[2][3]=fmaf(a2,vv.w,m[2][3]);
        m[3][0]=fmaf(a3,vv.x,m[3][0]); m[3][1]=fmaf(a3,vv.y,m[3][1]); m[3][2]=fmaf(a3,vv.z,m[3][2]); m[3][3]=fmaf(a3,vv.w,m[3][3]);
    }
    size_t base = (size_t)bhc * 4096;
    #pragma unroll
    for (int i = 0; i < 4; i++) {
        float4 o = make_float4(m[i][0], m[i][1], m[i][2], m[i][3]);
        *(float4*)&Mb[base + (size_t)(d0 + i)*64 + e0] = o;
    }
    if (tid == 0) Pb[bhc] = expf(ctot);
}

// ---------------------------------------------------------------------------
// scan pass 2 (IN PLACE): MS: M_c -> S_c (state at chunk start).
// ---------------------------------------------------------------------------
__global__ __launch_bounds__(256)
void scan_pass2(float* __restrict__ MS, const float* __restrict__ Pb)
{
    int bh = blockIdx.x, tid = threadIdx.x;
    float st[16];
    #pragma unroll
    for (int i = 0; i < 16; i++) st[i] = 0.f;
    for (int c = 0; c < NC; c++) {
        size_t base = ((size_t)bh*NC + c) * 4096;
        float p = Pb[bh*NC + c];
        #pragma unroll
        for (int i = 0; i < 16; i++) {
            size_t e = base + tid + i*256;
            float m = MS[e];
            MS[e] = st[i];
            st[i] = fmaf(p, st[i], m);
        }
    }
}

// ---------------------------------------------------------------------------
// fused scan pass 3: A[t][s] = (s<=t)? g_s exp(cum[t]-cum[s]) (q_t.k_s) : 0
//   y[t] = A @ v + exp(cum[t]) * (q_t @ S_c);  y over q buffer (exact alias)
// ---------------------------------------------------------------------------
__global__ __launch_bounds__(256)
void scan_pass3(const u16* __restrict__ qbuf, const u16* __restrict__ kbuf,
                const u16* __restrict__ vbuf, const float* __restrict__ g,
                const float* __restrict__ dec, const float* __restrict__ Sb,
                u16* __restrict__ y)
{
    __shared__ float qs[64*64];
    __shared__ float kt[64*68];   // [d][s] padded; later reused as Ss
    __shared__ float vs[64*64];
    __shared__ u16   Aws[4096];
    __shared__ float dd[64], gg[64], cum[64];
    int tid = threadIdx.x;
    int bhc = blockIdx.x;
    int c = bhc & 31, h = (bhc >> 5) & 15, b = bhc >> 9;
    int t0 = c * CT;
    size_t rowbase = ((size_t)(b*TT + t0))*CC + h*DD;

    for (int i = tid; i < 4096; i += 256) {
        int s = i >> 6, d = i & 63;
        size_t gi = rowbase + (size_t)s*CC + d;
        qs[i]        = bf2f(qbuf[gi]);
        kt[d*68 + s] = bf2f(kbuf[gi]);
        vs[i]        = bf2f(vbuf[gi]);
    }
    if (tid < 64) {
        int gidx = (b*TT + t0 + tid)*HH + h;
        dd[tid] = dec[gidx];
        gg[tid] = g[gidx];
    }
    __syncthreads();
    if (tid == 0) {
        float cs = 0.f;
        for (int s = 0; s < 64; s++) { cs += logf(fmaxf(dd[s], 1e-30f)); cum[s] = cs; }
    }
    __syncthreads();

    const int tt0 = (tid >> 4) * 4, ss0 = (tid & 15) * 4;
    float a1[4][4] = {};
    for (int d = 0; d < 64; d++) {
        float4 kv = *(const float4*)&kt[d*68 + ss0];
        #pragma unroll
        for (int i = 0; i < 4; i++) {
            float qv = qs[(tt0 + i)*64 + d];
            a1[i][0] = fmaf(qv, kv.x, a1[i][0]);
            a1[i][1] = fmaf(qv, kv.y, a1[i][1]);
            a1[i][2] = fmaf(qv, kv.z, a1[i][2]);
            a1[i][3] = fmaf(qv, kv.w, a1[i][3]);
        }
    }
    #pragma unroll
    for (int i = 0; i < 4; i++) {
        int t = tt0 + i;
        float ct = cum[t];
        #pragma unroll
        for (int j = 0; j < 4; j++) {
            int s = ss0 + j;
            float w = (s <= t) ? gg[s] * expf(ct - cum[s]) : 0.f;
            Aws[t*64 + s] = f2bf(w * a1[i][j]);
        }
    }
    __syncthreads();
    float* Ss = kt;
    size_t sbase = (size_t)bhc * 4096;
    for (int i = tid; i < 4096; i += 256) Ss[i] = Sb[sbase + i];
    __syncthreads();

    const int e0 = ss0;
    float o1[4][4] = {}, o2[4][4] = {};
    for (int s = 0; s < 64; s++) {
        float4 vv = *(const float4*)&vs[s*64 + e0];
        #pragma unroll
        for (int i = 0; i < 4; i++) {
            float av = bf2f(Aws[(tt0 + i)*64 + s]);
            o1[i][0] = fmaf(av, vv.x, o1[i][0]);
            o1[i][1] = fmaf(av, vv.y, o1[i][1]);
            o1[i][2] = fmaf(av, vv.z, o1[i][2]);
            o1[i][3] = fmaf(av, vv.w, o1[i][3]);
        }
    }
    for (int d = 0; d < 64; d++) {
        float4 sv = *(const float4*)&Ss[d*64 + e0];
        #pragma unroll
        for (int i = 0; i < 4; i++) {
            float qv = qs[(tt0 + i)*64 + d];
            o2[i][0] = fmaf(qv, sv.x, o2[i][0]);
            o2[i][1] = fmaf(qv, sv.y, o2[i][1]);
            o2[i][2] = fmaf(qv, sv.z, o2[i][2]);
            o2[i][3] = fmaf(qv, sv.w, o2[i][3]);
        }
    }
    #pragma unroll
    for (int i = 0; i < 4; i++) {
        float cd = expf(cum[tt0 + i]);
        size_t obase = rowbase + (size_t)(tt0 + i)*CC + e0;
        #pragma unroll
        for (int j = 0; j < 4; j++)
            y[obase + j] = f2bf(fmaf(cd, o2[i][j], o1[i][j]));
    }
}

// ---------------------------------------------------------------------------
// rmsnorm per row of 1024 (bf16 in/out)
// ---------------------------------------------------------------------------
__global__ __launch_bounds__(256)
void rmsnorm_kernel(const u16* __restrict__ yp, u16* __restrict__ yn)
{
    __shared__ float red[4];
    __shared__ float sscale;
    int row = blockIdx.x, tid = threadIdx.x;
    size_t base = (size_t)row*CC + tid*4;
    uint2 w = *(const uint2*)(yp + base);
    float v0 = bf2f((u16)(w.x & 0xffffu)), v1 = bf2f((u16)(w.x >> 16));
    float v2 = bf2f((u16)(w.y & 0xffffu)), v3 = bf2f((u16)(w.y >> 16));
    float p = v0*v0 + v1*v1 + v2*v2 + v3*v3;
    #pragma unroll
    for (int off = 32; off > 0; off >>= 1) p += __shfl_down(p, off, 64);
    if ((tid & 63) == 0) red[tid >> 6] = p;
    __syncthreads();
    if (tid == 0) {
        float tot = red[0] + red[1] + red[2] + red[3];
        sscale = rsqrtf(tot * (1.0f/1024.0f) + 1.1920928955078125e-07f);
    }
    __syncthreads();
    float sc = sscale;
    yn[base + 0] = f2bf(v0 * sc);
    yn[base + 1] = f2bf(v1 * sc);
    yn[base + 2] = f2bf(v2 * sc);
    yn[base + 3] = f2bf(v3 * sc);
}

// ---------------------------------------------------------------------------
// Workspace layout: identical to the PASSING round-3 layout (peak 48 MB + 64 B)
// ---------------------------------------------------------------------------
extern "C" void kernel_launch(void* const* d_in, const int* in_sizes, int n_in,
                              void* d_out, int out_size, void* d_ws, size_t ws_size,
                              hipStream_t stream)
{
    char* ws = (char*)d_ws;
    u16*   q    = (u16*)  (ws + 0*MB);
    u16*   k    = (u16*)  (ws + 8*MB);
    u16*   v    = (u16*)  (ws + 16*MB);
    float* hid  = (float*)(ws + 24*MB);
    float* g    = (float*)(ws + 28*MB);
    float* dec  = (float*)(ws + 28*MB + 262144);
    float* Pb   = (float*)(ws + 28*MB + 524288);
    float* MS   = (float*)(ws + 29*MB);
    u16*   yat  = q;                      // pass3 writes over q (exact alias)
    u16*   yn   = (u16*)  (ws + 32*MB);
    u16*   ypr  = (u16*)  (ws + 40*MB);
    u16*   h1   = (u16*)  (ws + 0*MB);
    u32*   flags= (u32*)  (ws + 48*MB);

    const void* x   = d_in[0];
    const void* Wq  = d_in[1];
    const void* Wk  = d_in[2];
    const void* Wv  = d_in[3];
    const void* Wm1 = d_in[4];
    const void* bm1 = d_in[5];
    const void* Wm2 = d_in[6];
    const void* bm2 = d_in[7];
    const void* Wpr = d_in[8];
    const void* Wfc = d_in[9];
    const void* Wcp = d_in[10];

    InPtrs ip;
    for (int i = 0; i < 11; i++) { ip.p[i] = d_in[i]; ip.n[i] = in_sizes[i]; }
    sniff_kernel<<<1, 64, 0, stream>>>(ip, flags);

    // meta net: hid = relu(x @ Wm1^T + bm1)  (f32 out)
    gemm_nt<1><<<dim3(2, 32), 256, 0, stream>>>(x, Wm1, hid, bm1, NTOK, HID, CC, flags, 0, 4, 5, -2);
    meta2_kernel<<<NTOK/16, 256, 0, stream>>>(hid, Wm2, bm2, g, dec, flags);
    // qkv (bf16 out)
    gemm_nt<0><<<dim3(8, 32), 256, 0, stream>>>(x, Wq, q, nullptr, NTOK, CC, CC, flags, 0, 1, -1, -1);
    gemm_nt<0><<<dim3(8, 32), 256, 0, stream>>>(x, Wk, k, nullptr, NTOK, CC, CC, flags, 0, 2, -1, -1);
    gemm_nt<0><<<dim3(8, 32), 256, 0, stream>>>(x, Wv, v, nullptr, NTOK, CC, CC, flags, 0, 3, -1, -1);
    // chunked gated linear-attention scan
    scan_pass1<<<NCHK, 256, 0, stream>>>(k, v, g, dec, MS, Pb);
    scan_pass2<<<NBH, 256, 0, stream>>>(MS, Pb);
    scan_pass3<<<NCHK, 256, 0, stream>>>(q, k, v, g, dec, MS, yat);
    // proj + rmsnorm + squared-relu MLP (+ residual in last GEMM)
    gemm_nt<0><<<dim3(8, 32), 256, 0, stream>>>(yat, Wpr, ypr, nullptr, NTOK, CC, CC, flags, -1, 8, -1, -1);
    rmsnorm_kernel<<<NTOK, 256, 0, stream>>>(ypr, yn);
    gemm_nt<2><<<dim3(32, 32), 256, 0, stream>>>(yn, Wfc, h1, nullptr, NTOK, FFD, CC, flags, -1, 9, -1, -1);
    gemm_nt<3><<<dim3(8, 32), 256, 0, stream>>>(h1, Wcp, d_out, ypr, NTOK, CC, FFD, flags, -1, 10, -1, 0);
}

// Round 6
// 603.400 us; speedup vs baseline: 3.1293x; 1.2434x over previous
//
#include <hip/hip_runtime.h>
#include <math.h>

// Problem constants
#define BB   2
#define TT   2048
#define CC   1024
#define HH   16
#define DD   64
#define HID  256
#define FFD  4096
#define NTOK (BB*TT)        // 4096
#define CT   64             // scan chunk length
#define NC   (TT/CT)        // 32 chunks per sequence
#define NBH  (BB*HH)        // 32 sequences
#define NCHK (NBH*NC)       // 1024 chunk-blocks
#define MB   (1048576ULL)

typedef unsigned short u16;
typedef unsigned int   u32;
typedef __attribute__((ext_vector_type(8))) short frag8;   // 8 bf16 = 4 VGPRs
typedef __attribute__((ext_vector_type(4))) float f32x4;

__device__ __forceinline__ float bf2f(u16 h){
    union { u32 u; float f; } c; c.u = ((u32)h) << 16; return c.f;
}
__device__ __forceinline__ u16 f2bf(float f){
    union { float f; u32 u; } c; c.f = f;
    u32 u = c.u;
    u += 0x7FFFu + ((u >> 16) & 1u);   // RNE
    return (u16)(u >> 16);
}
// idx >= 0: runtime flag (1 = f32). idx == -1: bf16. idx == -2: f32.
__device__ __forceinline__ bool is_f32(const u32* flags, int idx) {
    if (idx == -2) return true;
    if (idx < 0)  return false;
    return flags[idx] != 0;
}

// ---------------------------------------------------------------------------
// dtype sniffer (unchanged from passing round-3/5 version)
// ---------------------------------------------------------------------------
struct InPtrs { const void* p[11]; int n[11]; };

__global__ __launch_bounds__(64)
void sniff_kernel(InPtrs ip, u32* __restrict__ flags)
{
    int lane = threadIdx.x;
    u32 f0 = 0;
    for (int i = 0; i < 11; i++) {
        const u16* p = (const u16*)ip.p[i];
        int cap = ip.n[i] < 256 ? ip.n[i] : 256;
        bool ok = true;
        for (int j = lane; j < cap; j += 64) {
            u16 u = p[j];
            u32 e = (u >> 7) & 0xFFu;
            bool good = (u == 0u) || (u == 0x8000u) || (e >= 64u && e < 192u);
            ok = ok && good;
        }
        unsigned long long ball = __ballot(ok);
        u32 fl = (ball == ~0ull) ? 0u : 1u;
        if (ip.n[i] < 64) fl = f0;       // tiny tensors inherit x's dtype
        if (i == 0) f0 = fl;
        if (lane == 0) flags[i] = fl;
    }
}

// ---------------------------------------------------------------------------
// stage one 16-element k-chunk (bf16 or f32 src) into regs as bf16
// ---------------------------------------------------------------------------
__device__ __forceinline__ void stage16(const void* p, size_t off, bool f32,
                                        u16* buf)
{
    if (f32) {
        const float* s = (const float*)p + off;
        #pragma unroll
        for (int i = 0; i < 16; i += 4) {
            float4 u = *(const float4*)(s + i);
            buf[i]   = f2bf(u.x); buf[i+1] = f2bf(u.y);
            buf[i+2] = f2bf(u.z); buf[i+3] = f2bf(u.w);
        }
    } else {
        const u16* s = (const u16*)p + off;
        *(uint4*)buf     = *(const uint4*)s;
        *(uint4*)(buf+8) = *(const uint4*)(s + 8);
    }
}

// XCD-aware block remap: blocks i=0..NB-1 (NB%8==0) -> (bm, bn) such that
// each XCD (i%8) owns a compact bm-major stripe. Pure permutation.
__device__ __forceinline__ void xcd_map(int i, int NB, int gx, int& bm, int& bn)
{
    int per = NB >> 3;
    int iq  = (i & 7) * per + (i >> 3);
    bm = iq / gx;
    bn = iq % gx;
}

// ---------------------------------------------------------------------------
// NT GEMM, MFMA core (verified R5): C[M,N] = epilogue( A[M,K+] @ B[N,K+]^T )
// MODE: 0 plain, 2 relu^2, 3 +res(bf16).  Split-K via blockIdx.y (z):
// koff = z*K, f32 output offset z*M*N (use oi=-2 for partials).
// 128x128 tile, BK=32, 256 thr = 4 waves, wave = 4x4 of 16x16x32 MFMA, LDK=40.
// ---------------------------------------------------------------------------
template<int MODE>
__global__ __launch_bounds__(256)
void gemm_nt(const void* __restrict__ Av, const void* __restrict__ Bv,
             void* __restrict__ Cm, const void* __restrict__ aux,
             int M, int N, int K, int lda, int ldb,
             const u32* __restrict__ flags, int ai, int bi, int oi)
{
    const bool af32 = is_f32(flags, ai);
    const bool bf32 = is_f32(flags, bi);
    const bool of32 = is_f32(flags, oi);

    constexpr int LDK = 40;
    __shared__ u16 As[128 * LDK];
    __shared__ u16 Bs[128 * LDK];
    const int tid = threadIdx.x;
    int bm, bn;
    xcd_map(blockIdx.x, gridDim.x, N >> 7, bm, bn);
    const int z = blockIdx.y;
    const size_t koff = (size_t)z * K;

    const int row  = tid >> 1;          // 0..127
    const int half = tid & 1;           // which 16-element k-chunk
    const size_t aoff = (size_t)(bm*128 + row)*lda + koff + half*16;
    const size_t boff = (size_t)(bn*128 + row)*ldb + koff + half*16;
    u16* sA = &As[row*LDK + half*16];
    u16* sB = &Bs[row*LDK + half*16];

    const int wave = tid >> 6, lane = tid & 63;
    const int lm = lane & 15, quad = lane >> 4;
    const int wm = (wave >> 1) * 64, wn = (wave & 1) * 64;

    f32x4 acc[4][4];
    #pragma unroll
    for (int i = 0; i < 4; i++)
        #pragma unroll
        for (int j = 0; j < 4; j++)
            acc[i][j] = (f32x4){0.f, 0.f, 0.f, 0.f};

    for (int k0 = 0; k0 < K; k0 += 32) {
        u16 abuf[16], bbuf[16];
        stage16(Av, aoff + k0, af32, abuf);
        stage16(Bv, boff + k0, bf32, bbuf);
        __syncthreads();
        *(uint4*)sA = *(uint4*)abuf; *(uint4*)(sA + 8) = *(uint4*)(abuf + 8);
        *(uint4*)sB = *(uint4*)bbuf; *(uint4*)(sB + 8) = *(uint4*)(bbuf + 8);
        __syncthreads();
        frag8 af[4], bf[4];
        #pragma unroll
        for (int i = 0; i < 4; i++) {
            af[i] = *(frag8*)&As[(wm + i*16 + lm)*LDK + quad*8];
            bf[i] = *(frag8*)&Bs[(wn + i*16 + lm)*LDK + quad*8];
        }
        #pragma unroll
        for (int i = 0; i < 4; i++)
            #pragma unroll
            for (int j = 0; j < 4; j++)
                acc[i][j] = __builtin_amdgcn_mfma_f32_16x16x32_bf16(
                    af[i], bf[j], acc[i][j], 0, 0, 0);
    }

    const size_t coff = (size_t)z * M * N;
    // C/D map (m89/m91): col = lane&15, row = quad*4 + reg
    #pragma unroll
    for (int i = 0; i < 4; i++) {
        #pragma unroll
        for (int j = 0; j < 4; j++) {
            const int gcol = bn*128 + wn + j*16 + lm;
            #pragma unroll
            for (int r = 0; r < 4; r++) {
                const int grow = bm*128 + wm + i*16 + quad*4 + r;
                size_t off = (size_t)grow * N + gcol;
                float vv = acc[i][j][r];
                if constexpr (MODE == 2) { vv = fmaxf(vv, 0.f); vv = vv * vv; }
                if constexpr (MODE == 3) { vv += bf2f(((const u16*)aux)[off]); }
                if (of32) ((float*)Cm)[coff + off] = vv;
                else      ((u16*)Cm)[off]          = f2bf(vv);
            }
        }
    }
}

// ---------------------------------------------------------------------------
// Fused QKV + meta1 GEMM: A = x [4096,1024]; bn 0..7 -> q, 8..15 -> k,
// 16..23 -> v (bf16 [4096,1024] each); bn 24..25 -> hid = relu(x@Wm1^T + bm1)
// (f32 [4096,256]). 832 blocks, XCD-swizzled.
// ---------------------------------------------------------------------------
__global__ __launch_bounds__(256)
void gemm_qkvm(const void* __restrict__ Xv,
               const void* __restrict__ Wq, const void* __restrict__ Wk,
               const void* __restrict__ Wv, const void* __restrict__ Wm1,
               const void* __restrict__ bm1,
               u16* __restrict__ q, u16* __restrict__ k, u16* __restrict__ v,
               float* __restrict__ hid, const u32* __restrict__ flags)
{
    constexpr int LDK = 40;
    __shared__ u16 As[128 * LDK];
    __shared__ u16 Bs[128 * LDK];
    const int tid = threadIdx.x;
    int bm, bn;
    xcd_map(blockIdx.x, 832, 26, bm, bn);

    const int bsel = bn >> 3;                    // 0 q, 1 k, 2 v, 3 meta
    const void* Bv = (bsel == 0) ? Wq : (bsel == 1) ? Wk : (bsel == 2) ? Wv : Wm1;
    const bool af32 = is_f32(flags, 0);
    const bool bf32 = is_f32(flags, 1 + bsel);

    const int row  = tid >> 1;
    const int half = tid & 1;
    const size_t aoff = (size_t)(bm*128 + row)*CC + half*16;
    const size_t boff = (size_t)((bn & 7)*128 + row)*CC + half*16;
    u16* sA = &As[row*LDK + half*16];
    u16* sB = &Bs[row*LDK + half*16];

    const int wave = tid >> 6, lane = tid & 63;
    const int lm = lane & 15, quad = lane >> 4;
    const int wm = (wave >> 1) * 64, wn = (wave & 1) * 64;

    f32x4 acc[4][4];
    #pragma unroll
    for (int i = 0; i < 4; i++)
        #pragma unroll
        for (int j = 0; j < 4; j++)
            acc[i][j] = (f32x4){0.f, 0.f, 0.f, 0.f};

    for (int k0 = 0; k0 < CC; k0 += 32) {
        u16 abuf[16], bbuf[16];
        stage16(Xv, aoff + k0, af32, abuf);
        stage16(Bv, boff + k0, bf32, bbuf);
        __syncthreads();
        *(uint4*)sA = *(uint4*)abuf; *(uint4*)(sA + 8) = *(uint4*)(abuf + 8);
        *(uint4*)sB = *(uint4*)bbuf; *(uint4*)(sB + 8) = *(uint4*)(bbuf + 8);
        __syncthreads();
        frag8 af[4], bf[4];
        #pragma unroll
        for (int i = 0; i < 4; i++) {
            af[i] = *(frag8*)&As[(wm + i*16 + lm)*LDK + quad*8];
            bf[i] = *(frag8*)&Bs[(wn + i*16 + lm)*LDK + quad*8];
        }
        #pragma unroll
        for (int i = 0; i < 4; i++)
            #pragma unroll
            for (int j = 0; j < 4; j++)
                acc[i][j] = __builtin_amdgcn_mfma_f32_16x16x32_bf16(
                    af[i], bf[j], acc[i][j], 0, 0, 0);
    }

    if (bsel < 3) {
        u16* outp = (bsel == 0) ? q : (bsel == 1) ? k : v;
        #pragma unroll
        for (int i = 0; i < 4; i++) {
            #pragma unroll
            for (int j = 0; j < 4; j++) {
                const int gcol = (bn & 7)*128 + wn + j*16 + lm;
                #pragma unroll
                for (int r = 0; r < 4; r++) {
                    const int grow = bm*128 + wm + i*16 + quad*4 + r;
                    outp[(size_t)grow * CC + gcol] = f2bf(acc[i][j][r]);
                }
            }
        }
    } else {
        const bool biasf = is_f32(flags, 5);
        #pragma unroll
        for (int i = 0; i < 4; i++) {
            #pragma unroll
            for (int j = 0; j < 4; j++) {
                const int gcol = (bn & 7)*128 + wn + j*16 + lm;   // 0..255
                float bia = biasf ? ((const float*)bm1)[gcol]
                                  : bf2f(((const u16*)bm1)[gcol]);
                #pragma unroll
                for (int r = 0; r < 4; r++) {
                    const int grow = bm*128 + wm + i*16 + quad*4 + r;
                    hid[(size_t)grow * HID + gcol] = fmaxf(acc[i][j][r] + bia, 0.f);
                }
            }
        }
    }
}

// ---------------------------------------------------------------------------
// meta2: sur = sigmoid(hid @ Wm2^T + bm2); g = sur, dec = 1 - sur
// ---------------------------------------------------------------------------
__global__ __launch_bounds__(256)
void meta2_kernel(const float* __restrict__ hid, const void* __restrict__ Wm2,
                  const void* __restrict__ bm2, float* __restrict__ g,
                  float* __restrict__ dec, const u32* __restrict__ flags)
{
    const bool wf = is_f32(flags, 6);
    const bool bf = is_f32(flags, 7);
    __shared__ float hs[16][257];
    __shared__ float wsm[16][257];
    int tid  = threadIdx.x;
    int tok0 = blockIdx.x * 16;
    for (int i = tid; i < 16*256; i += 256) {
        wsm[i >> 8][i & 255] = wf ? ((const float*)Wm2)[i] : bf2f(((const u16*)Wm2)[i]);
        hs [i >> 8][i & 255] = hid[(size_t)tok0*256 + i];
    }
    __syncthreads();
    int tok = tid >> 4, hh = tid & 15;
    float s = 0.f;
    #pragma unroll 8
    for (int kk = 0; kk < 256; kk++) s = fmaf(hs[tok][kk], wsm[hh][kk], s);
    s += bf ? ((const float*)bm2)[hh] : bf2f(((const u16*)bm2)[hh]);
    float sg = 1.f / (1.f + expf(-s));
    int idx = (tok0 + tok) * HH + hh;
    g[idx]   = sg;
    dec[idx] = 1.f - sg;
}

// ---------------------------------------------------------------------------
// scan pass 1 (unchanged from R5)
// ---------------------------------------------------------------------------
__global__ __launch_bounds__(256)
void scan_pass1(const u16* __restrict__ kbuf, const u16* __restrict__ vbuf,
                const float* __restrict__ g, const float* __restrict__ dec,
                float* __restrict__ Mb, float* __restrict__ Pb)
{
    __shared__ float ks[64*64];
    __shared__ float vs[64*64];
    __shared__ float dd[64], gg[64], cum[64], sw[64];
    int tid = threadIdx.x;
    int bhc = blockIdx.x;
    int c = bhc & 31, h = (bhc >> 5) & 15, b = bhc >> 9;
    int t0 = c * CT;
    size_t rowbase = ((size_t)(b*TT + t0))*CC + h*DD;

    for (int i = tid; i < 4096; i += 256) {
        int s = i >> 6, d = i & 63;
        ks[i] = bf2f(kbuf[rowbase + (size_t)s*CC + d]);
        vs[i] = bf2f(vbuf[rowbase + (size_t)s*CC + d]);
    }
    if (tid < 64) {
        int gidx = (b*TT + t0 + tid)*HH + h;
        dd[tid] = dec[gidx];
        gg[tid] = g[gidx];
    }
    __syncthreads();
    if (tid == 0) {
        float cs = 0.f;
        for (int s = 0; s < 64; s++) { cs += logf(fmaxf(dd[s], 1e-30f)); cum[s] = cs; }
    }
    __syncthreads();
    float ctot = cum[63];
    if (tid < 64) sw[tid] = gg[tid] * expf(ctot - cum[tid]);
    __syncthreads();

    int d0 = (tid >> 4) * 4, e0 = (tid & 15) * 4;
    float m[4][4] = {};
    for (int s = 0; s < 64; s++) {
        float w = sw[s];
        float4 kv = *(const float4*)&ks[s*64 + d0];
        float4 vv = *(const float4*)&vs[s*64 + e0];
        float a0 = w*kv.x, a1 = w*kv.y, a2 = w*kv.z, a3 = w*kv.w;
        m[0][0]=fmaf(a0,vv.x,m[0][0]); m[0][1]=fmaf(a0,vv.y,m[0][1]); m[0][2]=fmaf(a0,vv.z,m[0][2]); m[0][3]=fmaf(a0,vv.w,m[0][3]);
        m[1][0]=fmaf(a1,vv.x,m[1][0]); m[1][1]=fmaf(a1,vv.y,m[1][1]); m[1][2]=fmaf(a1,vv.z,m[1][2]); m[1][3]=fmaf(a1,vv.w,m[1][3]);
        m[2][0]=fmaf(a2,vv.x,m[2][0]); m[2][1]=fmaf(a2,vv.y,m[2][1]); m[2][2]=fmaf(a2,vv.z,m[2][2]); m[2][3]=fmaf(a2,vv.w,m[2][3]);
        m[3][0]=fmaf(a3,vv.x,m[3][0]); m[3][1]=fmaf(a3,vv.y,m[3][1]); m[3][2]=fmaf(a3,vv.z,m[3][2]); m[3][3]=fmaf(a3,vv.w,m[3][3]);
    }
    size_t base = (size_t)bhc * 4096;
    #pragma unroll
    for (int i = 0; i < 4; i++) {
        float4 o = make_float4(m[i][0], m[i][1], m[i][2], m[i][3]);
        *(float4*)&Mb[base + (size_t)(d0 + i)*64 + e0] = o;
    }
    if (tid == 0) Pb[bhc] = expf(ctot);
}

// ---------------------------------------------------------------------------
// scan pass 2 (unchanged)
// ---------------------------------------------------------------------------
__global__ __launch_bounds__(256)
void scan_pass2(float* __restrict__ MS, const float* __restrict__ Pb)
{
    int bh = blockIdx.x, tid = threadIdx.x;
    float st[16];
    #pragma unroll
    for (int i = 0; i < 16; i++) st[i] = 0.f;
    for (int c = 0; c < NC; c++) {
        size_t base = ((size_t)bh*NC + c) * 4096;
        float p = Pb[bh*NC + c];
        #pragma unroll
        for (int i = 0; i < 16; i++) {
            size_t e = base + tid + i*256;
            float m = MS[e];
            MS[e] = st[i];
            st[i] = fmaf(p, st[i], m);
        }
    }
}

// ---------------------------------------------------------------------------
// fused scan pass 3 (unchanged)
// ---------------------------------------------------------------------------
__global__ __launch_bounds__(256)
void scan_pass3(const u16* __restrict__ qbuf, const u16* __restrict__ kbuf,
                const u16* __restrict__ vbuf, const float* __restrict__ g,
                const float* __restrict__ dec, const float* __restrict__ Sb,
                u16* __restrict__ y)
{
    __shared__ float qs[64*64];
    __shared__ float kt[64*68];   // [d][s] padded; later reused as Ss
    __shared__ float vs[64*64];
    __shared__ u16   Aws[4096];
    __shared__ float dd[64], gg[64], cum[64];
    int tid = threadIdx.x;
    int bhc = blockIdx.x;
    int c = bhc & 31, h = (bhc >> 5) & 15, b = bhc >> 9;
    int t0 = c * CT;
    size_t rowbase = ((size_t)(b*TT + t0))*CC + h*DD;

    for (int i = tid; i < 4096; i += 256) {
        int s = i >> 6, d = i & 63;
        size_t gi = rowbase + (size_t)s*CC + d;
        qs[i]        = bf2f(qbuf[gi]);
        kt[d*68 + s] = bf2f(kbuf[gi]);
        vs[i]        = bf2f(vbuf[gi]);
    }
    if (tid < 64) {
        int gidx = (b*TT + t0 + tid)*HH + h;
        dd[tid] = dec[gidx];
        gg[tid] = g[gidx];
    }
    __syncthreads();
    if (tid == 0) {
        float cs = 0.f;
        for (int s = 0; s < 64; s++) { cs += logf(fmaxf(dd[s], 1e-30f)); cum[s] = cs; }
    }
    __syncthreads();

    const int tt0 = (tid >> 4) * 4, ss0 = (tid & 15) * 4;
    float a1[4][4] = {};
    for (int d = 0; d < 64; d++) {
        float4 kv = *(const float4*)&kt[d*68 + ss0];
        #pragma unroll
        for (int i = 0; i < 4; i++) {
            float qv = qs[(tt0 + i)*64 + d];
            a1[i][0] = fmaf(qv, kv.x, a1[i][0]);
            a1[i][1] = fmaf(qv, kv.y, a1[i][1]);
            a1[i][2] = fmaf(qv, kv.z, a1[i][2]);
            a1[i][3] = fmaf(qv, kv.w, a1[i][3]);
        }
    }
    #pragma unroll
    for (int i = 0; i < 4; i++) {
        int t = tt0 + i;
        float ct = cum[t];
        #pragma unroll
        for (int j = 0; j < 4; j++) {
            int s = ss0 + j;
            float w = (s <= t) ? gg[s] * expf(ct - cum[s]) : 0.f;
            Aws[t*64 + s] = f2bf(w * a1[i][j]);
        }
    }
    __syncthreads();
    float* Ss = kt;
    size_t sbase = (size_t)bhc * 4096;
    for (int i = tid; i < 4096; i += 256) Ss[i] = Sb[sbase + i];
    __syncthreads();

    const int e0 = ss0;
    float o1[4][4] = {}, o2[4][4] = {};
    for (int s = 0; s < 64; s++) {
        float4 vv = *(const float4*)&vs[s*64 + e0];
        #pragma unroll
        for (int i = 0; i < 4; i++) {
            float av = bf2f(Aws[(tt0 + i)*64 + s]);
            o1[i][0] = fmaf(av, vv.x, o1[i][0]);
            o1[i][1] = fmaf(av, vv.y, o1[i][1]);
            o1[i][2] = fmaf(av, vv.z, o1[i][2]);
            o1[i][3] = fmaf(av, vv.w, o1[i][3]);
        }
    }
    for (int d = 0; d < 64; d++) {
        float4 sv = *(const float4*)&Ss[d*64 + e0];
        #pragma unroll
        for (int i = 0; i < 4; i++) {
            float qv = qs[(tt0 + i)*64 + d];
            o2[i][0] = fmaf(qv, sv.x, o2[i][0]);
            o2[i][1] = fmaf(qv, sv.y, o2[i][1]);
            o2[i][2] = fmaf(qv, sv.z, o2[i][2]);
            o2[i][3] = fmaf(qv, sv.w, o2[i][3]);
        }
    }
    #pragma unroll
    for (int i = 0; i < 4; i++) {
        float cd = expf(cum[tt0 + i]);
        size_t obase = rowbase + (size_t)(tt0 + i)*CC + e0;
        #pragma unroll
        for (int j = 0; j < 4; j++)
            y[obase + j] = f2bf(fmaf(cd, o2[i][j], o1[i][j]));
    }
}

// ---------------------------------------------------------------------------
// rmsnorm v2: y = p0 + p1 (f32 split-K partials); writes bf16 residual yres
// and bf16 normed yn.
// ---------------------------------------------------------------------------
__global__ __launch_bounds__(256)
void rmsnorm_kernel(const float* __restrict__ p0, const float* __restrict__ p1,
                    u16* __restrict__ yres, u16* __restrict__ yn)
{
    __shared__ float red[4];
    __shared__ float sscale;
    int row = blockIdx.x, tid = threadIdx.x;
    size_t base = (size_t)row*CC + tid*4;
    float4 a = *(const float4*)&p0[base];
    float4 b = *(const float4*)&p1[base];
    float v0 = a.x + b.x, v1 = a.y + b.y, v2 = a.z + b.z, v3 = a.w + b.w;
    yres[base + 0] = f2bf(v0);
    yres[base + 1] = f2bf(v1);
    yres[base + 2] = f2bf(v2);
    yres[base + 3] = f2bf(v3);
    float p = v0*v0 + v1*v1 + v2*v2 + v3*v3;
    #pragma unroll
    for (int off = 32; off > 0; off >>= 1) p += __shfl_down(p, off, 64);
    if ((tid & 63) == 0) red[tid >> 6] = p;
    __syncthreads();
    if (tid == 0) {
        float tot = red[0] + red[1] + red[2] + red[3];
        sscale = rsqrtf(tot * (1.0f/1024.0f) + 1.1920928955078125e-07f);
    }
    __syncthreads();
    float sc = sscale;
    yn[base + 0] = f2bf(v0 * sc);
    yn[base + 1] = f2bf(v1 * sc);
    yn[base + 2] = f2bf(v2 * sc);
    yn[base + 3] = f2bf(v3 * sc);
}

// ---------------------------------------------------------------------------
// Workspace (peak 48 MB + 64 B):
// Phase A: q 0..8 | k 8..16 | v 16..24 | hid 24..28 | g/dec/Pb 28..28.5 |
//          MS 29..45.  Phase B: yat=q (alias) | p0 8..24 (over k,v) |
//          p1 24..40 (over hid,g,dec,Pb,MS-head) | yres 0..8 (over yat after
//          proj) | yn 40..48 | h1 8..40 (over p0,p1 after rmsnorm).
// flags @ 48 MB.
// ---------------------------------------------------------------------------
extern "C" void kernel_launch(void* const* d_in, const int* in_sizes, int n_in,
                              void* d_out, int out_size, void* d_ws, size_t ws_size,
                              hipStream_t stream)
{
    char* ws = (char*)d_ws;
    u16*   q    = (u16*)  (ws + 0*MB);
    u16*   k    = (u16*)  (ws + 8*MB);
    u16*   v    = (u16*)  (ws + 16*MB);
    float* hid  = (float*)(ws + 24*MB);
    float* g    = (float*)(ws + 28*MB);
    float* dec  = (float*)(ws + 28*MB + 262144);
    float* Pb   = (float*)(ws + 28*MB + 524288);
    float* MS   = (float*)(ws + 29*MB);
    u16*   yat  = q;                      // pass3 writes over q (exact alias)
    float* p0   = (float*)(ws + 8*MB);    // proj split-K partials (f32)
    u16*   yres = (u16*)  (ws + 0*MB);    // over yat after proj
    u16*   yn   = (u16*)  (ws + 40*MB);
    u16*   h1   = (u16*)  (ws + 8*MB);    // over p0/p1 after rmsnorm
    u32*   flags= (u32*)  (ws + 48*MB);

    InPtrs ip;
    for (int i = 0; i < 11; i++) { ip.p[i] = d_in[i]; ip.n[i] = in_sizes[i]; }
    sniff_kernel<<<1, 64, 0, stream>>>(ip, flags);

    // fused qkv + meta1 (832 blocks, XCD-swizzled)
    gemm_qkvm<<<832, 256, 0, stream>>>(d_in[0], d_in[1], d_in[2], d_in[3],
                                       d_in[4], d_in[5], q, k, v, hid, flags);
    meta2_kernel<<<NTOK/16, 256, 0, stream>>>(hid, d_in[6], d_in[7], g, dec, flags);
    // chunked gated linear-attention scan
    scan_pass1<<<NCHK, 256, 0, stream>>>(k, v, g, dec, MS, Pb);
    scan_pass2<<<NBH, 256, 0, stream>>>(MS, Pb);
    scan_pass3<<<NCHK, 256, 0, stream>>>(q, k, v, g, dec, MS, yat);
    // proj: split-K x2 -> f32 partials p0,p1 (512 concurrent blocks)
    gemm_nt<0><<<dim3(256, 2), 256, 0, stream>>>(yat, d_in[8], p0, nullptr,
        NTOK, CC, 512, CC, CC, flags, -1, 8, -2);
    // rmsnorm: combine partials, emit residual (bf16) + normed (bf16)
    rmsnorm_kernel<<<NTOK, 256, 0, stream>>>(p0, p0 + (size_t)NTOK*CC, yres, yn);
    // squared-relu MLP
    gemm_nt<2><<<dim3(1024, 1), 256, 0, stream>>>(yn, d_in[9], h1, nullptr,
        NTOK, FFD, CC, CC, CC, flags, -1, 9, -1);
    gemm_nt<3><<<dim3(256, 1), 256, 0, stream>>>(h1, d_in[10], d_out, yres,
        NTOK, CC, FFD, FFD, FFD, flags, -1, 10, 0);
}